// Round 3
// baseline (4832.231 us; speedup 1.0000x reference)
//
#include <hip/hip_runtime.h>
#include <hip/hip_fp16.h>

#define B_ 128
#define T_ 64
#define I_ 128
#define H_ 256
#define UF 6
#define EPSF 1e-8f
#define NBLK 512

static __device__ __forceinline__ float rcpf(float x) { return __builtin_amdgcn_rcpf(x); }
static __device__ __forceinline__ float h2f_lo(unsigned u) {
    return __half2float(__ushort_as_half((unsigned short)(u & 0xffffu)));
}
static __device__ __forceinline__ float h2f_hi(unsigned u) {
    return __half2float(__ushort_as_half((unsigned short)(u >> 16)));
}

// ---------------- K0: pack params to fp16, zero sync flags.
// A = -sigma*log2e, B = sigma*mu*log2e, W = w*erev (|W| = w since erev = +-1)
__global__ __launch_bounds__(256) void pack_params(
    const float* __restrict__ smu, const float* __restrict__ ssig,
    const float* __restrict__ sw,  const float* __restrict__ serev,
    const float* __restrict__ imu, const float* __restrict__ isig,
    const float* __restrict__ iw,  const float* __restrict__ ierev,
    unsigned* __restrict__ AB_s, unsigned short* __restrict__ WE_s,
    unsigned* __restrict__ AB_i, uint2* __restrict__ WQ_i, int* __restrict__ flags)
{
    const float L2E = 1.4426950408889634f;
    int idx = blockIdx.x * 256 + threadIdx.x;   // grid covers H_*H_ = 65536
    {
        float s = isig[idx], m = imu[idx];
        unsigned a = __half_as_ushort(__float2half_rn(-s * L2E));
        unsigned b = __half_as_ushort(__float2half_rn(s * m * L2E));
        AB_i[idx] = a | (b << 16);
    }
    if (idx < 64 * H_) {                        // W quads: [i4][jg] as uint2
        int i4 = idx >> 8, jg = idx & 255;
        unsigned p0 = __half_as_ushort(__float2half_rn(iw[(4*i4+0)*H_+jg] * ierev[(4*i4+0)*H_+jg]));
        unsigned p1 = __half_as_ushort(__float2half_rn(iw[(4*i4+1)*H_+jg] * ierev[(4*i4+1)*H_+jg]));
        unsigned p2 = __half_as_ushort(__float2half_rn(iw[(4*i4+2)*H_+jg] * ierev[(4*i4+2)*H_+jg]));
        unsigned p3 = __half_as_ushort(__float2half_rn(iw[(4*i4+3)*H_+jg] * ierev[(4*i4+3)*H_+jg]));
        WQ_i[idx] = make_uint2(p0 | (p1 << 16), p2 | (p3 << 16));
    }
    if (idx < I_ * H_) {
        float s = ssig[idx], m = smu[idx], w = sw[idx], e = serev[idx];
        unsigned a = __half_as_ushort(__float2half_rn(-s * L2E));
        unsigned b = __half_as_ushort(__float2half_rn(s * m * L2E));
        AB_s[idx] = a | (b << 16);
        WE_s[idx] = __half_as_ushort(__float2half_rn(w * e));
    }
    if (idx < NBLK * 16) flags[idx] = 0;
}

// ---------------- K1: recurrent LTC. 4 blocks per batch (j-split by 64), flag-synced.
// block bx: batch b = bx & 127, quarter q = bx >> 7, peers bx ^ (128q') on same XCD.
// 512 threads = j(64) x c(8); 2 blocks co-resident per CU (LDS ~75 KB) so the
// serial reduce/exchange of one block overlaps the other's gate compute.
__global__ __launch_bounds__(512, 4) void ltc_rec(
    const float* __restrict__ x, const float* __restrict__ in_w, const float* __restrict__ in_b,
    const unsigned* __restrict__ AB_s, const unsigned short* __restrict__ WE_s,
    const unsigned* __restrict__ AB_i, const uint2* __restrict__ WQ_i,
    const float* __restrict__ vleak, const float* __restrict__ gleak, const float* __restrict__ cm,
    const float* __restrict__ out_w, const float* __restrict__ out_b,
    float* __restrict__ Vg, int* __restrict__ flags,
    float* __restrict__ out, float* __restrict__ hT)
{
    __shared__ unsigned ABl[H_ * 64];     // 64 KB: [i/2][j][2], fp16 A|B<<16
    __shared__ float Vs[H_];
    __shared__ float xs[I_];
    __shared__ float rn[8 * 64], rd[8 * 64];  // unfold partials
    __shared__ float qn[8 * 64], qd[8 * 64];  // sensing partials (per t)

    const int bx  = blockIdx.x;
    const int b   = bx & 127;
    const int q   = bx >> 7;             // 0..3 = j-quarter
    const int tid = threadIdx.x;
    const int j   = tid & 63;
    const int c   = tid >> 6;            // 0..7, wave-uniform
    const int jg  = (q << 6) + j;

    // stage own-quarter internal AB into LDS, pair-packed for ds_read_b64
    for (int k = tid; k < H_ * 64; k += 512) {
        int i = k >> 6, jl = k & 63;
        ABl[((i >> 1) << 7) + (jl << 1) + (i & 1)] = AB_i[(i << 8) + (q << 6) + jl];
    }

    float cmt = 0.f, glvl = 0.f, dc = 0.f, owj = 0.f, obj = 0.f, iwv = 0.f, ibv = 0.f;
    if (tid < 64) {
        cmt = cm[jg] * (float)UF;
        float gl = gleak[jg];
        glvl = gl * vleak[jg];
        dc = cmt + gl + EPSF;
        owj = out_w[jg]; obj = out_b[jg];
    }
    if (tid < I_) { iwv = in_w[tid]; ibv = in_b[tid]; }
    if (tid < H_) Vs[tid] = 0.f;
    __syncthreads();

    const float* xrow = x + (size_t)b * (T_ * I_);
    int p = 0;

    for (int t = 0; t < T_; ++t) {
        if (tid < I_) xs[tid] = fmaf(xrow[t * I_ + tid], iwv, ibv);
        __syncthreads();

        // ---- sensing partials: 16 i's per thread, streamed from L2 (no pre-reduce;
        // folded into the per-unfold reduce via qn/qd)
        {
            float pn = 0.f, pd = 0.f;
            const int i0 = c << 4;
            #pragma unroll
            for (int ii = 0; ii < 16; ++ii) {
                const int i = i0 + ii;
                unsigned ab = AB_s[(i << 8) + jg];
                float wv = __half2float(__ushort_as_half(WE_s[(i << 8) + jg]));
                float r  = rcpf(1.f + exp2f(fmaf(h2f_lo(ab), xs[i], h2f_hi(ab))));
                pn = fmaf(wv, r, pn);
                pd = fmaf(fabsf(wv), r, pd);
            }
            qn[(c << 6) + j] = pn; qd[(c << 6) + j] = pd;
        }
        // (qn/qd stores are protected by the first unfold's partial barrier)

        // ---- 6 unfolds with 4-way cross-block exchange
        for (int u = 0; u < UF; ++u) {
            float nm = 0.f, dn = 0.f;
            const int i0 = c << 5;
            #pragma unroll
            for (int ii = 0; ii < 32; ii += 4) {
                const int i = i0 + ii;
                const float4 v4 = *reinterpret_cast<const float4*>(Vs + i);  // wave-uniform
                const int pb = ((i >> 1) << 7) + (j << 1);
                unsigned ab0 = ABl[pb],       ab1 = ABl[pb + 1];
                unsigned ab2 = ABl[pb + 128], ab3 = ABl[pb + 129];
                uint2 w4 = WQ_i[((i >> 2) << 8) + jg];
                float r0 = rcpf(1.f + exp2f(fmaf(h2f_lo(ab0), v4.x, h2f_hi(ab0))));
                float r1 = rcpf(1.f + exp2f(fmaf(h2f_lo(ab1), v4.y, h2f_hi(ab1))));
                float r2 = rcpf(1.f + exp2f(fmaf(h2f_lo(ab2), v4.z, h2f_hi(ab2))));
                float r3 = rcpf(1.f + exp2f(fmaf(h2f_lo(ab3), v4.w, h2f_hi(ab3))));
                float w0 = h2f_lo(w4.x), w1 = h2f_hi(w4.x);
                float w2 = h2f_lo(w4.y), w3 = h2f_hi(w4.y);
                nm = fmaf(w0, r0, nm); dn = fmaf(fabsf(w0), r0, dn);
                nm = fmaf(w1, r1, nm); dn = fmaf(fabsf(w1), r1, dn);
                nm = fmaf(w2, r2, nm); dn = fmaf(fabsf(w2), r2, dn);
                nm = fmaf(w3, r3, nm); dn = fmaf(fabsf(w3), r3, dn);
            }
            rn[(c << 6) + j] = nm; rd[(c << 6) + j] = dn;
            __syncthreads();
            ++p;
            float* Vgb = Vg + (p & 1) * (B_ * H_) + (b << 8);
            if (tid < 64) {      // wave 0: reduce, update, publish, spin
                float N = 0.f, D = 0.f;
                #pragma unroll
                for (int k = 0; k < 8; ++k) {
                    N += rn[(k << 6) + tid] + qn[(k << 6) + tid];
                    D += rd[(k << 6) + tid] + qd[(k << 6) + tid];
                }
                float Vn = (fmaf(Vs[jg], cmt, glvl) + N) * rcpf(D + dc);
                Vs[jg] = Vn;
                __hip_atomic_store(Vgb + jg, Vn, __ATOMIC_RELAXED, __HIP_MEMORY_SCOPE_AGENT);
                if (tid == 0)    // release: waits this wave's vmcnt -> Vg stores visible
                    __hip_atomic_store(flags + (bx << 4), p, __ATOMIC_RELEASE, __HIP_MEMORY_SCOPE_AGENT);
                if (tid < 3) {
                    const int pbx = b + (((q + tid + 1) & 3) << 7);
                    while (__hip_atomic_load(flags + (pbx << 4), __ATOMIC_ACQUIRE, __HIP_MEMORY_SCOPE_AGENT) < p) {}
                }
            }
            __syncthreads();
            if (tid < H_ && (tid >> 6) != q)
                Vs[tid] = __hip_atomic_load(Vgb + tid, __ATOMIC_RELAXED, __HIP_MEMORY_SCOPE_AGENT);
            __syncthreads();
        }

        if (tid < 64) out[((size_t)b * T_ + t) * H_ + jg] = fmaf(Vs[jg], owj, obj);
    }
    if (tid < 64) hT[(b << 8) + jg] = Vs[jg];
}

extern "C" void kernel_launch(void* const* d_in, const int* in_sizes, int n_in,
                              void* d_out, int out_size, void* d_ws, size_t ws_size,
                              hipStream_t stream) {
    const float* x     = (const float*)d_in[0];
    const float* in_w  = (const float*)d_in[1];
    const float* in_b  = (const float*)d_in[2];
    const float* smu   = (const float*)d_in[3];
    const float* ssig  = (const float*)d_in[4];
    const float* sw    = (const float*)d_in[5];
    const float* serev = (const float*)d_in[6];
    const float* imu   = (const float*)d_in[7];
    const float* isig  = (const float*)d_in[8];
    const float* iw    = (const float*)d_in[9];
    const float* ierev = (const float*)d_in[10];
    const float* vleak = (const float*)d_in[11];
    const float* gleak = (const float*)d_in[12];
    const float* cmv   = (const float*)d_in[13];
    const float* ow    = (const float*)d_in[14];
    const float* ob    = (const float*)d_in[15];

    float* out = (float*)d_out;                 // [B, T, H]
    float* hT  = out + (size_t)B_ * T_ * H_;    // [B, H]

    char* w = (char*)d_ws;
    unsigned* AB_i  = (unsigned*)(w);                      // 256 KB  [i][jg]
    uint2*    WQ_i  = (uint2*)(w + (256 << 10));           // 128 KB  [i4][jg]
    unsigned* AB_s  = (unsigned*)(w + (384 << 10));        // 128 KB  [i][jg]
    unsigned short* WE_s = (unsigned short*)(w + (512 << 10)); // 64 KB [i][jg]
    float*    Vg    = (float*)(w + (576 << 10));           // 256 KB  [2][B][H]
    int*      flags = (int*)(w + (832 << 10));             //  32 KB  [512][16]

    pack_params<<<dim3(H_ * H_ / 256), dim3(256), 0, stream>>>(
        smu, ssig, sw, serev, imu, isig, iw, ierev, AB_s, WE_s, AB_i, WQ_i, flags);

    ltc_rec<<<dim3(NBLK), dim3(512), 0, stream>>>(
        x, in_w, in_b, AB_s, WE_s, AB_i, WQ_i, vleak, gleak, cmv, ow, ob,
        Vg, flags, out, hT);
}

// Round 4
// 1066.996 us; speedup vs baseline: 4.5288x; 4.5288x over previous
//
#include <hip/hip_runtime.h>
#include <hip/hip_fp16.h>

#define B_ 128
#define T_ 64
#define I_ 128
#define H_ 256
#define UF 6
#define EPSF 1e-8f

typedef _Float16 f16x2 __attribute__((ext_vector_type(2)));
union H2U { __half2 h; f16x2 v; unsigned u; };

static __device__ __forceinline__ float rcpf(float x) { return __builtin_amdgcn_rcpf(x); }
static __device__ __forceinline__ float h2f_lo(unsigned u) {
    return __half2float(__ushort_as_half((unsigned short)(u & 0xffffu)));
}
static __device__ __forceinline__ float h2f_hi(unsigned u) {
    return __half2float(__ushort_as_half((unsigned short)(u >> 16)));
}

// ---------------- K0: pack params.
// Internal, pair-packed fp16: ABp[pair][jg] = (A(2p)|A(2p+1)<<16, B(2p)|B(2p+1)<<16),
// Wp[pair][jg] = we(2p)|we(2p+1)<<16 with A=-sigma*log2e, B=sigma*mu*log2e, we=w*erev.
// Sensing: AB_s[i][jg] = A|B<<16 (fp16), WE_s[i][jg] = we (fp16).
__global__ __launch_bounds__(256) void pack_params(
    const float* __restrict__ smu, const float* __restrict__ ssig,
    const float* __restrict__ sw,  const float* __restrict__ serev,
    const float* __restrict__ imu, const float* __restrict__ isig,
    const float* __restrict__ iw,  const float* __restrict__ ierev,
    unsigned* __restrict__ AB_s, unsigned short* __restrict__ WE_s,
    uint2* __restrict__ ABp, unsigned* __restrict__ Wp)
{
    const float L2E = 1.4426950408889634f;
    int idx = blockIdx.x * 256 + threadIdx.x;   // 32768 = 128 x 256
    int r = idx >> 8, jg = idx & 255;
    {   // internal pair r = (2r, 2r+1)
        int i0 = 2 * r, i1 = 2 * r + 1;
        unsigned a0 = __half_as_ushort(__float2half_rn(-isig[i0 * H_ + jg] * L2E));
        unsigned a1 = __half_as_ushort(__float2half_rn(-isig[i1 * H_ + jg] * L2E));
        unsigned b0 = __half_as_ushort(__float2half_rn(isig[i0 * H_ + jg] * imu[i0 * H_ + jg] * L2E));
        unsigned b1 = __half_as_ushort(__float2half_rn(isig[i1 * H_ + jg] * imu[i1 * H_ + jg] * L2E));
        ABp[idx] = make_uint2(a0 | (a1 << 16), b0 | (b1 << 16));
        unsigned w0 = __half_as_ushort(__float2half_rn(iw[i0 * H_ + jg] * ierev[i0 * H_ + jg]));
        unsigned w1 = __half_as_ushort(__float2half_rn(iw[i1 * H_ + jg] * ierev[i1 * H_ + jg]));
        Wp[idx] = w0 | (w1 << 16);
    }
    {   // sensing element (i=r, jg)
        float s = ssig[idx], m = smu[idx];
        unsigned a = __half_as_ushort(__float2half_rn(-s * L2E));
        unsigned b = __half_as_ushort(__float2half_rn(s * m * L2E));
        AB_s[idx] = a | (b << 16);
        WE_s[idx] = __half_as_ushort(__float2half_rn(sw[idx] * serev[idx]));
    }
}

// ---------------- K1: recurrent LTC. 2 blocks per batch (j-half each), 1 block/CU,
// all 256 blocks co-resident. Internal params register-cached (48 VGPRs). Gates in
// packed fp16 with f32 dot2 accumulation. Cross-block V exchange via self-tagged
// 4B relaxed agent atomics (tag<<16 | fp16(V)), double-buffered; poll hidden under
// the own-half (phase A) gate compute.
__global__ __launch_bounds__(1024, 4) void ltc_rec(
    const float* __restrict__ x, const float* __restrict__ in_w, const float* __restrict__ in_b,
    const unsigned* __restrict__ AB_s, const unsigned short* __restrict__ WE_s,
    const uint2* __restrict__ ABp, const unsigned* __restrict__ Wp,
    const float* __restrict__ vleak, const float* __restrict__ gleak, const float* __restrict__ cm,
    const float* __restrict__ out_w, const float* __restrict__ out_b,
    unsigned* __restrict__ Vg4,
    float* __restrict__ out, float* __restrict__ hT)
{
    __shared__ unsigned V2u[H_ / 2];          // packed fp16 V pairs (full H)
    __shared__ float xs[I_];
    __shared__ float rn[8 * 128], rd[8 * 128];

    const int bx  = blockIdx.x;
    const int b   = bx & 127;
    const int jh  = bx >> 7;                  // own j-half
    const int tid = threadIdx.x;
    const int j   = tid & 127;
    const int c   = tid >> 7;                 // 0..7, wave-uniform
    const int jg  = (jh << 7) + j;
    const int pjbase = ((jh ^ 1) << 7);

    // ---- register-cache internal params: 8 own + 8 peer pairs per thread
    unsigned ra[16], rb[16], rw[16];
    {
        const int po = (jh << 6) + (c << 3);
        const int pp = ((jh ^ 1) << 6) + (c << 3);
        #pragma unroll
        for (int k = 0; k < 8; ++k) {
            uint2 u0 = ABp[((po + k) << 8) + jg];
            ra[k] = u0.x; rb[k] = u0.y; rw[k] = Wp[((po + k) << 8) + jg];
            uint2 u1 = ABp[((pp + k) << 8) + jg];
            ra[8 + k] = u1.x; rb[8 + k] = u1.y; rw[8 + k] = Wp[((pp + k) << 8) + jg];
        }
    }

    float cmt = 0.f, glvl = 0.f, dc = 0.f, owj = 0.f, obj = 0.f, iwv = 0.f, ibv = 0.f;
    if (tid < 128) {
        cmt = cm[jg] * (float)UF;
        float gl = gleak[jg];
        glvl = gl * vleak[jg];
        dc = cmt + gl + EPSF;
        owj = out_w[jg]; obj = out_b[jg];
        iwv = in_w[tid]; ibv = in_b[tid];
    }
    if (tid < H_ / 2) V2u[tid] = 0u;          // V(0) = 0 (both halves)
    float vreg = 0.f;
    __syncthreads();

    const float* xrow = x + (size_t)b * (T_ * I_);
    const __half2 one2 = __float2half2_rn(1.0f);

    for (int t = 0; t < T_; ++t) {
        if (tid < I_) xs[tid] = fmaf(xrow[t * I_ + tid], iwv, ibv);
        __syncthreads();

        // ---- sensing partials (f32, streamed from L2), kept in regs for all 6 unfolds
        float qsn = 0.f, qsd = 0.f;
        {
            const int i0s = c << 4;
            #pragma unroll
            for (int ii = 0; ii < 16; ++ii) {
                const int i = i0s + ii;
                unsigned ab = AB_s[(i << 8) + jg];
                float wv = __half2float(__ushort_as_half(WE_s[(i << 8) + jg]));
                float r  = rcpf(1.f + exp2f(fmaf(h2f_lo(ab), xs[i], h2f_hi(ab))));
                qsn = fmaf(wv, r, qsn);
                qsd = fmaf(fabsf(wv), r, qsd);
            }
        }

        for (int u = 0; u < UF; ++u) {
            const int p = t * UF + u + 1;
            float nm = qsn, dn = qsd;

            // ---- phase A: own-half i's (V fresh in V2u own region)
            {
                const int vb = (jh << 6) + (c << 3);
                #pragma unroll
                for (int k = 0; k < 8; ++k) {
                    H2U v2; v2.u = V2u[vb + k];           // broadcast
                    H2U av; av.u = ra[k];
                    H2U bv; bv.u = rb[k];
                    __half2 z = __hfma2(av.h, v2.h, bv.h);
                    __half2 e = h2exp2(z);
                    __half2 s = __hadd2(e, one2);
                    H2U rv; rv.h = h2rcp(s);
                    H2U ws; ws.u = rw[k];
                    H2U wa; wa.u = ws.u & 0x7fff7fffu;
                    nm = __builtin_amdgcn_fdot2(ws.v, rv.v, nm, false);
                    dn = __builtin_amdgcn_fdot2(wa.v, rv.v, dn, false);
                }
            }

            // ---- poll peer V(p-1), hidden under phase A; write peer V2u region
            if (p > 1 && tid < 128) {
                const unsigned* src = Vg4 + (size_t)((p - 1) & 1) * (B_ * H_) + (b << 8) + pjbase + tid;
                unsigned v;
                do { v = __hip_atomic_load(src, __ATOMIC_RELAXED, __HIP_MEMORY_SCOPE_AGENT); }
                while ((v >> 16) != (unsigned)(p - 1));
                unsigned hv = v & 0xffffu;
                unsigned hv1 = (unsigned)__shfl_down((int)hv, 1);
                if (!(tid & 1)) V2u[(pjbase >> 1) + (tid >> 1)] = hv | (hv1 << 16);
            }
            __syncthreads();

            // ---- phase B: peer-half i's
            {
                const int vb = ((jh ^ 1) << 6) + (c << 3);
                #pragma unroll
                for (int k = 0; k < 8; ++k) {
                    H2U v2; v2.u = V2u[vb + k];
                    H2U av; av.u = ra[8 + k];
                    H2U bv; bv.u = rb[8 + k];
                    __half2 z = __hfma2(av.h, v2.h, bv.h);
                    __half2 e = h2exp2(z);
                    __half2 s = __hadd2(e, one2);
                    H2U rv; rv.h = h2rcp(s);
                    H2U ws; ws.u = rw[8 + k];
                    H2U wa; wa.u = ws.u & 0x7fff7fffu;
                    nm = __builtin_amdgcn_fdot2(ws.v, rv.v, nm, false);
                    dn = __builtin_amdgcn_fdot2(wa.v, rv.v, dn, false);
                }
            }
            rn[(c << 7) + j] = nm; rd[(c << 7) + j] = dn;
            __syncthreads();

            // ---- reduce + update + publish (waves 0-1)
            if (tid < 128) {
                float N = 0.f, D = 0.f;
                #pragma unroll
                for (int k2 = 0; k2 < 8; ++k2) { N += rn[(k2 << 7) + tid]; D += rd[(k2 << 7) + tid]; }
                float Vn = (fmaf(vreg, cmt, glvl) + N) * rcpf(D + dc);
                vreg = Vn;
                unsigned h0 = __half_as_ushort(__float2half_rn(Vn));
                __hip_atomic_store(Vg4 + (size_t)(p & 1) * (B_ * H_) + (b << 8) + jg,
                                   ((unsigned)p << 16) | h0,
                                   __ATOMIC_RELAXED, __HIP_MEMORY_SCOPE_AGENT);
                unsigned h1 = (unsigned)__shfl_down((int)h0, 1);
                if (!(tid & 1)) V2u[jg >> 1] = h0 | (h1 << 16);
                if (u == UF - 1) out[((size_t)b * T_ + t) * H_ + jg] = fmaf(Vn, owj, obj);
            }
            __syncthreads();
        }
    }
    if (tid < 128) hT[(b << 8) + jg] = vreg;
}

extern "C" void kernel_launch(void* const* d_in, const int* in_sizes, int n_in,
                              void* d_out, int out_size, void* d_ws, size_t ws_size,
                              hipStream_t stream) {
    const float* x     = (const float*)d_in[0];
    const float* in_w  = (const float*)d_in[1];
    const float* in_b  = (const float*)d_in[2];
    const float* smu   = (const float*)d_in[3];
    const float* ssig  = (const float*)d_in[4];
    const float* sw    = (const float*)d_in[5];
    const float* serev = (const float*)d_in[6];
    const float* imu   = (const float*)d_in[7];
    const float* isig  = (const float*)d_in[8];
    const float* iw    = (const float*)d_in[9];
    const float* ierev = (const float*)d_in[10];
    const float* vleak = (const float*)d_in[11];
    const float* gleak = (const float*)d_in[12];
    const float* cmv   = (const float*)d_in[13];
    const float* ow    = (const float*)d_in[14];
    const float* ob    = (const float*)d_in[15];

    float* out = (float*)d_out;                 // [B, T, H]
    float* hT  = out + (size_t)B_ * T_ * H_;    // [B, H]

    char* w = (char*)d_ws;
    uint2*          ABp  = (uint2*)(w);                         // 256 KB [pair][jg]
    unsigned*       Wp   = (unsigned*)(w + (256 << 10));        // 128 KB [pair][jg]
    unsigned*       AB_s = (unsigned*)(w + (384 << 10));        // 128 KB [i][jg]
    unsigned short* WE_s = (unsigned short*)(w + (512 << 10));  //  64 KB [i][jg]
    unsigned*       Vg4  = (unsigned*)(w + (576 << 10));        // 256 KB [2][B][H]

    pack_params<<<dim3(128), dim3(256), 0, stream>>>(
        smu, ssig, sw, serev, imu, isig, iw, ierev, AB_s, WE_s, ABp, Wp);

    ltc_rec<<<dim3(256), dim3(1024), 0, stream>>>(
        x, in_w, in_b, AB_s, WE_s, ABp, Wp, vleak, gleak, cmv, ow, ob,
        Vg4, out, hT);
}

// Round 5
// 1017.003 us; speedup vs baseline: 4.7514x; 1.0492x over previous
//
#include <hip/hip_runtime.h>
#include <hip/hip_fp16.h>

#define B_ 128
#define T_ 64
#define I_ 128
#define H_ 256
#define UF 6
#define EPSF 1e-8f

typedef _Float16 f16x2 __attribute__((ext_vector_type(2)));
union H2U { __half2 h; f16x2 v; unsigned u; };

static __device__ __forceinline__ float rcpf(float x) { return __builtin_amdgcn_rcpf(x); }

// packed-fp16 dual gate: 2 sigmoids + f32 dot-accumulate into NM/DN
#define GATE2(VW, AK, BK, WK, NM, DN) {                        \
    H2U v2_; v2_.u = (VW);                                     \
    H2U av_; av_.u = (AK);                                     \
    H2U bv_; bv_.u = (BK);                                     \
    __half2 z_ = __hfma2(av_.h, v2_.h, bv_.h);                 \
    __half2 e_ = h2exp2(z_);                                   \
    __half2 s_ = __hadd2(e_, __float2half2_rn(1.0f));          \
    H2U rv_; rv_.h = h2rcp(s_);                                \
    H2U ws_; ws_.u = (WK);                                     \
    H2U wa_; wa_.u = ws_.u & 0x7fff7fffu;                      \
    NM = __builtin_amdgcn_fdot2(ws_.v, rv_.v, NM, false);      \
    DN = __builtin_amdgcn_fdot2(wa_.v, rv_.v, DN, false);      \
}

// ---------------- K0: pack params to pair-packed fp16, zero the exchange tags.
// A = -sigma*log2e, B = sigma*mu*log2e, W = w*erev (|W| = w since erev = +-1).
// Internal: ABp[pair][jg] = (A0|A1<<16, B0|B1<<16), Wp[pair][jg]; pair = i/2 (128 pairs).
// Sensing:  SAB[pair][jg], SW[pair][jg]; pair = i/2 (64 pairs).
__global__ __launch_bounds__(256) void pack_params(
    const float* __restrict__ smu, const float* __restrict__ ssig,
    const float* __restrict__ sw,  const float* __restrict__ serev,
    const float* __restrict__ imu, const float* __restrict__ isig,
    const float* __restrict__ iw,  const float* __restrict__ ierev,
    uint2* __restrict__ ABp, unsigned* __restrict__ Wp,
    uint2* __restrict__ SAB, unsigned* __restrict__ SW,
    unsigned* __restrict__ Vg4)
{
    const float L2E = 1.4426950408889634f;
    int idx = blockIdx.x * 256 + threadIdx.x;   // 32768 = 128 x 256
    int r = idx >> 8, jg = idx & 255;
    {   // internal pair r = (2r, 2r+1)
        int i0 = 2 * r, i1 = i0 + 1;
        unsigned a0 = __half_as_ushort(__float2half_rn(-isig[i0 * H_ + jg] * L2E));
        unsigned a1 = __half_as_ushort(__float2half_rn(-isig[i1 * H_ + jg] * L2E));
        unsigned b0 = __half_as_ushort(__float2half_rn(isig[i0 * H_ + jg] * imu[i0 * H_ + jg] * L2E));
        unsigned b1 = __half_as_ushort(__float2half_rn(isig[i1 * H_ + jg] * imu[i1 * H_ + jg] * L2E));
        ABp[idx] = make_uint2(a0 | (a1 << 16), b0 | (b1 << 16));
        unsigned w0 = __half_as_ushort(__float2half_rn(iw[i0 * H_ + jg] * ierev[i0 * H_ + jg]));
        unsigned w1 = __half_as_ushort(__float2half_rn(iw[i1 * H_ + jg] * ierev[i1 * H_ + jg]));
        Wp[idx] = w0 | (w1 << 16);
    }
    if (idx < 64 * H_) {    // sensing pair r = (2r, 2r+1), r < 64
        int i0 = 2 * r, i1 = i0 + 1;
        unsigned a0 = __half_as_ushort(__float2half_rn(-ssig[i0 * H_ + jg] * L2E));
        unsigned a1 = __half_as_ushort(__float2half_rn(-ssig[i1 * H_ + jg] * L2E));
        unsigned b0 = __half_as_ushort(__float2half_rn(ssig[i0 * H_ + jg] * smu[i0 * H_ + jg] * L2E));
        unsigned b1 = __half_as_ushort(__float2half_rn(ssig[i1 * H_ + jg] * smu[i1 * H_ + jg] * L2E));
        SAB[idx] = make_uint2(a0 | (a1 << 16), b0 | (b1 << 16));
        unsigned w0 = __half_as_ushort(__float2half_rn(sw[i0 * H_ + jg] * serev[i0 * H_ + jg]));
        unsigned w1 = __half_as_ushort(__float2half_rn(sw[i1 * H_ + jg] * serev[i1 * H_ + jg]));
        SW[idx] = w0 | (w1 << 16);
    }
    Vg4[idx] = 0u;              // zero exchange tags (2*B*H = 65536 words)
    Vg4[idx + 32768] = 0u;
}

// ---------------- K1: recurrent LTC. 2 blocks per batch (j-half each), 1 block/CU,
// all 256 blocks co-resident. Lane map tid = j*8 + c (c = i-chunk, low 3 bits) so the
// 8 partials per neuron reduce via shfl_xor inside each wave (no LDS, no serial tail).
// All params register-cached as packed fp16; V exchanged cross-block via self-tagged
// relaxed agent atomics (tag<<16 | fp16(V)), double-buffered, poll hidden under phase A.
__global__ __launch_bounds__(1024, 4) void ltc_rec(
    const float* __restrict__ x, const float* __restrict__ in_w, const float* __restrict__ in_b,
    const uint2* __restrict__ ABp, const unsigned* __restrict__ Wp,
    const uint2* __restrict__ SAB, const unsigned* __restrict__ SW,
    const float* __restrict__ vleak, const float* __restrict__ gleak, const float* __restrict__ cm,
    const float* __restrict__ out_w, const float* __restrict__ out_b,
    unsigned* __restrict__ Vg4,
    float* __restrict__ out, float* __restrict__ hT)
{
    __shared__ __align__(16) unsigned V2u[H_ / 2];   // packed fp16 V pairs (full H)
    __shared__ __align__(16) unsigned xs2[I_ / 2];   // packed fp16 xm pairs

    const int bx  = blockIdx.x;
    const int b   = bx & 127;
    const int jh  = bx >> 7;                  // own j-half
    const int tid = threadIdx.x;
    const int c   = tid & 7;                  // i-chunk (low bits -> wave shfl reduce)
    const int j   = tid >> 3;                 // 0..127 local neuron
    const int jg  = (jh << 7) + j;
    const int pjbase = ((jh ^ 1) << 7);
    const int BH  = B_ * H_;

    // ---- register-cache params (packed fp16 pairs)
    unsigned ra[16], rb[16], rw[16];          // internal: 8 own + 8 peer pairs
    unsigned sa[8], sb[8], sw8[8];            // sensing: 8 pairs
    {
        const int po = (jh << 6) + (c << 3);
        const int pp = ((jh ^ 1) << 6) + (c << 3);
        const int ps = (c << 3);
        #pragma unroll
        for (int k = 0; k < 8; ++k) {
            uint2 u0 = ABp[((po + k) << 8) + jg];
            ra[k] = u0.x; rb[k] = u0.y; rw[k] = Wp[((po + k) << 8) + jg];
            uint2 u1 = ABp[((pp + k) << 8) + jg];
            ra[8 + k] = u1.x; rb[8 + k] = u1.y; rw[8 + k] = Wp[((pp + k) << 8) + jg];
            uint2 u2 = SAB[((ps + k) << 8) + jg];
            sa[k] = u2.x; sb[k] = u2.y; sw8[k] = SW[((ps + k) << 8) + jg];
        }
    }

    const float cmt  = cm[jg] * (float)UF;
    const float gl   = gleak[jg];
    const float glvl = gl * vleak[jg];
    const float dc   = cmt + gl + EPSF;
    const float owj  = out_w[jg], obj = out_b[jg];
    float iw0 = 0.f, iw1 = 0.f, ib0 = 0.f, ib1 = 0.f;
    if (tid < 64) { iw0 = in_w[2 * tid]; iw1 = in_w[2 * tid + 1];
                    ib0 = in_b[2 * tid]; ib1 = in_b[2 * tid + 1]; }
    if (tid < H_ / 2) V2u[tid] = 0u;
    float vreg = 0.f;

    const float* xrow = x + (size_t)b * (T_ * I_);

    for (int t = 0; t < T_; ++t) {
        if (tid < 64) {
            float2 xv = *reinterpret_cast<const float2*>(xrow + t * I_ + 2 * tid);
            __half2 hh = __floats2half2_rn(fmaf(xv.x, iw0, ib0), fmaf(xv.y, iw1, ib1));
            H2U u; u.h = hh; xs2[tid] = u.u;
        }
        __syncthreads();   // xs2 ready (and V2u init at t==0)

        // ---- sensing partials (packed fp16), kept in regs for all 6 unfolds
        float qsn = 0.f, qsd = 0.f;
        {
            const uint4 xa = *reinterpret_cast<const uint4*>(xs2 + (c << 3));
            const uint4 xb = *reinterpret_cast<const uint4*>(xs2 + (c << 3) + 4);
            GATE2(xa.x, sa[0], sb[0], sw8[0], qsn, qsd);
            GATE2(xa.y, sa[1], sb[1], sw8[1], qsn, qsd);
            GATE2(xa.z, sa[2], sb[2], sw8[2], qsn, qsd);
            GATE2(xa.w, sa[3], sb[3], sw8[3], qsn, qsd);
            GATE2(xb.x, sa[4], sb[4], sw8[4], qsn, qsd);
            GATE2(xb.y, sa[5], sb[5], sw8[5], qsn, qsd);
            GATE2(xb.z, sa[6], sb[6], sw8[6], qsn, qsd);
            GATE2(xb.w, sa[7], sb[7], sw8[7], qsn, qsd);
        }

        for (int u = 0; u < UF; ++u) {
            const int p = t * UF + u + 1;
            float nm = qsn, dn = qsd;

            // ---- phase A: own-half i's
            {
                const int vb = (jh << 6) + (c << 3);
                const uint4 va = *reinterpret_cast<const uint4*>(V2u + vb);
                const uint4 vb4 = *reinterpret_cast<const uint4*>(V2u + vb + 4);
                GATE2(va.x,  ra[0], rb[0], rw[0], nm, dn);
                GATE2(va.y,  ra[1], rb[1], rw[1], nm, dn);
                GATE2(va.z,  ra[2], rb[2], rw[2], nm, dn);
                GATE2(va.w,  ra[3], rb[3], rw[3], nm, dn);
                GATE2(vb4.x, ra[4], rb[4], rw[4], nm, dn);
                GATE2(vb4.y, ra[5], rb[5], rw[5], nm, dn);
                GATE2(vb4.z, ra[6], rb[6], rw[6], nm, dn);
                GATE2(vb4.w, ra[7], rb[7], rw[7], nm, dn);
            }

            // ---- waves 0-1: poll peer V(p-1), pack into peer V2u region
            if (p > 1 && tid < 128) {
                const unsigned want = (unsigned)(p - 1);
                const unsigned* src = Vg4 + (size_t)(want & 1) * BH + (b << 8) + pjbase + tid;
                unsigned v;
                do { v = __hip_atomic_load(src, __ATOMIC_RELAXED, __HIP_MEMORY_SCOPE_AGENT); }
                while ((v >> 16) != want);
                unsigned hv = v & 0xffffu;
                unsigned hv1 = (unsigned)__shfl_down((int)hv, 1);
                if (!(tid & 1)) V2u[(pjbase >> 1) + (tid >> 1)] = hv | (hv1 << 16);
            }
            __syncthreads();   // peer V2u ready

            // ---- phase B: peer-half i's
            {
                const int vb = ((jh ^ 1) << 6) + (c << 3);
                const uint4 va = *reinterpret_cast<const uint4*>(V2u + vb);
                const uint4 vb4 = *reinterpret_cast<const uint4*>(V2u + vb + 4);
                GATE2(va.x,  ra[8],  rb[8],  rw[8],  nm, dn);
                GATE2(va.y,  ra[9],  rb[9],  rw[9],  nm, dn);
                GATE2(va.z,  ra[10], rb[10], rw[10], nm, dn);
                GATE2(va.w,  ra[11], rb[11], rw[11], nm, dn);
                GATE2(vb4.x, ra[12], rb[12], rw[12], nm, dn);
                GATE2(vb4.y, ra[13], rb[13], rw[13], nm, dn);
                GATE2(vb4.z, ra[14], rb[14], rw[14], nm, dn);
                GATE2(vb4.w, ra[15], rb[15], rw[15], nm, dn);
            }

            // ---- in-wave reduce over c (8 lanes per neuron)
            nm += __shfl_xor(nm, 1); dn += __shfl_xor(dn, 1);
            nm += __shfl_xor(nm, 2); dn += __shfl_xor(dn, 2);
            nm += __shfl_xor(nm, 4); dn += __shfl_xor(dn, 4);

            // ---- update (all lanes redundantly), publish + own V2u write (c==0)
            float Vn = (fmaf(vreg, cmt, glvl) + nm) * rcpf(dn + dc);
            vreg = Vn;
            unsigned h0 = __half_as_ushort(__float2half_rn(Vn));
            if (c == 0)
                __hip_atomic_store(Vg4 + (size_t)(p & 1) * BH + (b << 8) + jg,
                                   ((unsigned)p << 16) | h0,
                                   __ATOMIC_RELAXED, __HIP_MEMORY_SCOPE_AGENT);
            unsigned h1 = (unsigned)__shfl_down((int)h0, 8);
            if (c == 0 && !(j & 1)) V2u[jg >> 1] = h0 | (h1 << 16);
            __syncthreads();   // own V2u ready for next phase A
        }

        if (c == 0) out[((size_t)b * T_ + t) * H_ + jg] = fmaf(vreg, owj, obj);
    }
    if (c == 0) hT[(b << 8) + jg] = vreg;
}

extern "C" void kernel_launch(void* const* d_in, const int* in_sizes, int n_in,
                              void* d_out, int out_size, void* d_ws, size_t ws_size,
                              hipStream_t stream) {
    const float* x     = (const float*)d_in[0];
    const float* in_w  = (const float*)d_in[1];
    const float* in_b  = (const float*)d_in[2];
    const float* smu   = (const float*)d_in[3];
    const float* ssig  = (const float*)d_in[4];
    const float* sw    = (const float*)d_in[5];
    const float* serev = (const float*)d_in[6];
    const float* imu   = (const float*)d_in[7];
    const float* isig  = (const float*)d_in[8];
    const float* iw    = (const float*)d_in[9];
    const float* ierev = (const float*)d_in[10];
    const float* vleak = (const float*)d_in[11];
    const float* gleak = (const float*)d_in[12];
    const float* cmv   = (const float*)d_in[13];
    const float* ow    = (const float*)d_in[14];
    const float* ob    = (const float*)d_in[15];

    float* out = (float*)d_out;                 // [B, T, H]
    float* hT  = out + (size_t)B_ * T_ * H_;    // [B, H]

    char* w = (char*)d_ws;
    uint2*    ABp = (uint2*)(w);                    // 256 KB [pair][jg]
    unsigned* Wp  = (unsigned*)(w + (256 << 10));   // 128 KB [pair][jg]
    uint2*    SAB = (uint2*)(w + (384 << 10));      // 128 KB [pair][jg]
    unsigned* SW  = (unsigned*)(w + (512 << 10));   //  64 KB [pair][jg]
    unsigned* Vg4 = (unsigned*)(w + (576 << 10));   // 256 KB [2][B][H] tag|fp16

    pack_params<<<dim3(128), dim3(256), 0, stream>>>(
        smu, ssig, sw, serev, imu, isig, iw, ierev, ABp, Wp, SAB, SW, Vg4);

    ltc_rec<<<dim3(256), dim3(1024), 0, stream>>>(
        x, in_w, in_b, ABp, Wp, SAB, SW, vleak, gleak, cmv, ow, ob,
        Vg4, out, hT);
}